// Round 8
// baseline (635.676 us; speedup 1.0000x reference)
//
#include <hip/hip_runtime.h>
#include <cfloat>

// Problem constants
#define N_ROWS 32768
#define N_CLS  2048
#define DIM    512

typedef __attribute__((ext_vector_type(8))) short short8;
typedef __attribute__((ext_vector_type(4))) short short4v;
typedef __attribute__((ext_vector_type(4))) float f32x4;
typedef __attribute__((ext_vector_type(16))) float f32x16;

__device__ __forceinline__ unsigned f2bf_bits(float x) {
    union { float f; unsigned u; } a; a.f = x;
    return (a.u + 0x7fffu + ((a.u >> 16) & 1u)) >> 16;   // RNE
}
__device__ __forceinline__ float bf_to_f(unsigned bits) {
    union { unsigned u; float f; } a; a.u = bits << 16;
    return a.f;
}
__device__ __forceinline__ void split_bf(float x, short &h, short &l) {
    unsigned hb = f2bf_bits(x);
    h = (short)hb;
    float r = x - bf_to_f(hb);          // exact residual
    l = (short)f2bf_bits(r);
}

// ---------------- pre-split fp32 -> (hi, lo) bf16 arrays ----------------
__global__ __launch_bounds__(256) void split_kernel(const float* __restrict__ src,
                                                    short* __restrict__ hi,
                                                    short* __restrict__ lo) {
    int idx = blockIdx.x * 256 + threadIdx.x;     // one float4 per thread
    float4 v = ((const float4*)src)[idx];
    short h0, h1, h2, h3, l0, l1, l2, l3;
    split_bf(v.x, h0, l0); split_bf(v.y, h1, l1);
    split_bf(v.z, h2, l2); split_bf(v.w, h3, l3);
    ((short4v*)hi)[idx] = (short4v){h0, h1, h2, h3};
    ((short4v*)lo)[idx] = (short4v){l0, l1, l2, l3};
}

// ---------------- m2[j] = sum_d muK[j,d]^2 ----------------
__global__ __launch_bounds__(256) void m2_kernel(const float* __restrict__ muK,
                                                 float* __restrict__ m2) {
    const int j = blockIdx.x;
    const int t = threadIdx.x;
    const float* r = muK + (size_t)j * DIM;
    float a = r[t], b = r[t + 256];
    float s = a * a + b * b;
    for (int off = 32; off; off >>= 1) s += __shfl_xor(s, off);
    __shared__ float sw[4];
    if ((t & 63) == 0) sw[t >> 6] = s;
    __syncthreads();
    if (t == 0) m2[j] = sw[0] + sw[1] + sw[2] + sw[3];
}

#define GLDS16(g, l) __builtin_amdgcn_global_load_lds( \
    (const __attribute__((address_space(1))) unsigned int*)(g), \
    (__attribute__((address_space(3))) unsigned int*)(l), 16, 0, 0)

// ---------------- concat-K bf16 GEMM: 32x32x16 MFMA, XOR bank swizzle ----------------
// S[i,j] = 2 * sum_{k<1536} A'[i,k] B'[j,k] - m2[j], A'=[Xh|Xh|Xl], B'=[Mh|Ml|Mh]
// LDS slot (row, c) holds global 16B k-chunk (c ^ sigma(row)), sigma(row)=(row>>1)&3.
// Wave computes 64x64 as 2x2 tiles of 32x32; K=16 per MFMA, 2 k-steps per BK=32.
// A/B operand layout: [row=lane&31][k=(lane>>5)*8+j]; C/D: col=lane&31,
// row=(reg&3)+8*(reg>>2)+4*(lane>>5)  [m74/m101-verified].
__global__ __launch_bounds__(256) void gemm_kernel(const short* __restrict__ Xh,
                                                   const short* __restrict__ Xl,
                                                   const short* __restrict__ Mh,
                                                   const short* __restrict__ Ml,
                                                   const float* __restrict__ m2,
                                                   float* __restrict__ S) {
    __shared__ __align__(16) short As[128 * 32];
    __shared__ __align__(16) short Bs[128 * 32];

    const int tid  = threadIdx.x;
    const int n0   = blockIdx.x * 128;   // class tile
    const int m0   = blockIdx.y * 128;   // row tile
    const int w    = tid >> 6;
    const int lane = tid & 63;
    const int wm   = (w >> 1) * 64;
    const int wn   = (w & 1) * 64;
    const int r31  = lane & 31;
    const int half = lane >> 5;          // which k-half this lane reads
    const int sig  = (r31 >> 1) & 3;     // sigma(row): row bits [2:1] == r31 bits [2:1]

    // staging chunk ids (16B chunks); LDS dest = uniform base + lane*16 (lane-linear).
    // Source k-chunk is XOR-swizzled by sigma(row) = (row>>1)&3 = (c>>3)&3.
    const int c0 = w * 128 + lane;
    const int c1 = c0 + 64;
    const size_t ga0 = (size_t)(m0 + (c0 >> 2)) * DIM + (size_t)(((c0 & 3) ^ ((c0 >> 3) & 3)) * 8);
    const size_t ga1 = (size_t)(m0 + (c1 >> 2)) * DIM + (size_t)(((c1 & 3) ^ ((c1 >> 3) & 3)) * 8);
    const size_t gb0 = (size_t)(n0 + (c0 >> 2)) * DIM + (size_t)(((c0 & 3) ^ ((c0 >> 3) & 3)) * 8);
    const size_t gb1 = (size_t)(n0 + (c1 >> 2)) * DIM + (size_t)(((c1 & 3) ^ ((c1 >> 3) & 3)) * 8);

    f32x16 acc00 = {0}, acc01 = {0}, acc10 = {0}, acc11 = {0};

#pragma unroll 1
    for (int seg = 0; seg < 3; ++seg) {
        const short* Ap = (seg == 2) ? Xl : Xh;
        const short* Bp = (seg == 1) ? Ml : Mh;
#pragma unroll 1
        for (int kt2 = 0; kt2 < 16; ++kt2) {
            const int kk = kt2 * 32;
            __syncthreads();
            GLDS16(Ap + ga0 + kk, &As[c0 * 8]);
            GLDS16(Ap + ga1 + kk, &As[c1 * 8]);
            GLDS16(Bp + gb0 + kk, &Bs[c0 * 8]);
            GLDS16(Bp + gb1 + kk, &Bs[c1 * 8]);
            __syncthreads();

#pragma unroll
            for (int ks = 0; ks < 2; ++ks) {
                const int slot = ((ks * 2 + half) ^ sig) * 8;   // 16B chunk within row
                short8 a0 = *(const short8*)&As[(wm + r31) * 32 + slot];
                short8 a1 = *(const short8*)&As[(wm + 32 + r31) * 32 + slot];
                short8 b0 = *(const short8*)&Bs[(wn + r31) * 32 + slot];
                short8 b1 = *(const short8*)&Bs[(wn + 32 + r31) * 32 + slot];
                acc00 = __builtin_amdgcn_mfma_f32_32x32x16_bf16(a0, b0, acc00, 0, 0, 0);
                acc01 = __builtin_amdgcn_mfma_f32_32x32x16_bf16(a0, b1, acc01, 0, 0, 0);
                acc10 = __builtin_amdgcn_mfma_f32_32x32x16_bf16(a1, b0, acc10, 0, 0, 0);
                acc11 = __builtin_amdgcn_mfma_f32_32x32x16_bf16(a1, b1, acc11, 0, 0, 0);
            }
        }
    }

    // epilogue: C/D layout col=lane&31, row=(r&3)+8*(r>>2)+4*(lane>>5)
#pragma unroll
    for (int tn = 0; tn < 2; ++tn) {
        const int col = n0 + wn + tn * 32 + r31;
        const float mm = m2[col];
#pragma unroll
        for (int tm = 0; tm < 2; ++tm) {
            const f32x16 a = tn == 0 ? (tm == 0 ? acc00 : acc10)
                                     : (tm == 0 ? acc01 : acc11);
            const int rb = m0 + wm + tm * 32 + 4 * half;
#pragma unroll
            for (int r = 0; r < 16; ++r) {
                const int row = rb + (r & 3) + 8 * (r >> 2);
                S[(size_t)row * N_CLS + col] = 2.0f * a[r] - mm;
            }
        }
    }
}

// ---------------- round-1 fallback GEMM (in-kernel split; needs no big ws) ----------------
#define LDR 40
__global__ __launch_bounds__(256) void gemm_fallback(const float* __restrict__ X,
                                                     const float* __restrict__ muK,
                                                     const float* __restrict__ m2,
                                                     float* __restrict__ S) {
    __shared__ __align__(16) short Ah[128 * LDR];
    __shared__ __align__(16) short Al[128 * LDR];
    __shared__ __align__(16) short Bh[128 * LDR];
    __shared__ __align__(16) short Bl[128 * LDR];
    const int tid  = threadIdx.x;
    const int n0   = blockIdx.x * 128;
    const int m0   = blockIdx.y * 128;
    const int w    = tid >> 6;
    const int lane = tid & 63;
    const int wm   = (w >> 1) * 64;
    const int wn   = (w & 1) * 64;
    const int l16  = lane & 15;
    const int quad = lane >> 4;
    f32x4 acc[4][4];
#pragma unroll
    for (int mt = 0; mt < 4; ++mt)
#pragma unroll
        for (int nt = 0; nt < 4; ++nt)
            acc[mt][nt] = (f32x4){0.f, 0.f, 0.f, 0.f};
    for (int kt = 0; kt < DIM; kt += 32) {
        __syncthreads();
#pragma unroll
        for (int i = 0; i < 4; ++i) {
            int idx = tid + 256 * i;
            int row = idx >> 3;
            int c4  = (idx & 7) * 4;
            float4 fa = *(const float4*)(X + (size_t)(m0 + row) * DIM + kt + c4);
            float4 fb = *(const float4*)(muK + (size_t)(n0 + row) * DIM + kt + c4);
            short h0, h1, h2, h3, l0, l1, l2, l3;
            split_bf(fa.x, h0, l0); split_bf(fa.y, h1, l1);
            split_bf(fa.z, h2, l2); split_bf(fa.w, h3, l3);
            *(short4v*)&Ah[row * LDR + c4] = (short4v){h0, h1, h2, h3};
            *(short4v*)&Al[row * LDR + c4] = (short4v){l0, l1, l2, l3};
            split_bf(fb.x, h0, l0); split_bf(fb.y, h1, l1);
            split_bf(fb.z, h2, l2); split_bf(fb.w, h3, l3);
            *(short4v*)&Bh[row * LDR + c4] = (short4v){h0, h1, h2, h3};
            *(short4v*)&Bl[row * LDR + c4] = (short4v){l0, l1, l2, l3};
        }
        __syncthreads();
        short8 ah[4], al[4];
#pragma unroll
        for (int mt = 0; mt < 4; ++mt) {
            int r = wm + mt * 16 + l16;
            ah[mt] = *(const short8*)&Ah[r * LDR + quad * 8];
            al[mt] = *(const short8*)&Al[r * LDR + quad * 8];
        }
#pragma unroll
        for (int nt = 0; nt < 4; ++nt) {
            int r = wn + nt * 16 + l16;
            short8 bh = *(const short8*)&Bh[r * LDR + quad * 8];
            short8 bl = *(const short8*)&Bl[r * LDR + quad * 8];
#pragma unroll
            for (int mt = 0; mt < 4; ++mt)
                acc[mt][nt] = __builtin_amdgcn_mfma_f32_16x16x32_bf16(ah[mt], bh, acc[mt][nt], 0, 0, 0);
#pragma unroll
            for (int mt = 0; mt < 4; ++mt)
                acc[mt][nt] = __builtin_amdgcn_mfma_f32_16x16x32_bf16(ah[mt], bl, acc[mt][nt], 0, 0, 0);
#pragma unroll
            for (int mt = 0; mt < 4; ++mt)
                acc[mt][nt] = __builtin_amdgcn_mfma_f32_16x16x32_bf16(al[mt], bh, acc[mt][nt], 0, 0, 0);
        }
    }
#pragma unroll
    for (int nt = 0; nt < 4; ++nt) {
        int col = n0 + wn + nt * 16 + l16;
        float mm = m2[col];
#pragma unroll
        for (int mt = 0; mt < 4; ++mt) {
            int rbase = m0 + wm + mt * 16 + quad * 4;
#pragma unroll
            for (int r = 0; r < 4; ++r)
                S[(size_t)(rbase + r) * N_CLS + col] = 2.0f * acc[mt][nt][r] - mm;
        }
    }
}

// ---------------- masked row softmax: wave = 4 consecutive rows, 2-row pipeline ----------
// In-place. Cached loads, NT stores. Mask hoisted (row-invariant).
__device__ __forceinline__ void sm_load_row(float* S, int row, int lane, f32x4* v) {
    const f32x4* pi = (const f32x4*)(S + (size_t)row * N_CLS);
#pragma unroll
    for (int i = 0; i < 8; ++i) v[i] = pi[i * 64 + lane];
}

__device__ __forceinline__ void sm_compute_store(float* S, int row, int lane,
                                                 unsigned msk, f32x4* v) {
    float mn = FLT_MAX, mx = -FLT_MAX;
#pragma unroll
    for (int i = 0; i < 8; ++i) {
        f32x4 s = v[i];
        mn = fminf(mn, fminf(fminf(s.x, s.y), fminf(s.z, s.w)));
        if (!((msk >> (i * 4 + 0)) & 1u)) mx = fmaxf(mx, s.x);
        if (!((msk >> (i * 4 + 1)) & 1u)) mx = fmaxf(mx, s.y);
        if (!((msk >> (i * 4 + 2)) & 1u)) mx = fmaxf(mx, s.z);
        if (!((msk >> (i * 4 + 3)) & 1u)) mx = fmaxf(mx, s.w);
    }
    for (int off = 32; off; off >>= 1) {
        mn = fminf(mn, __shfl_xor(mn, off));
        mx = fmaxf(mx, __shfl_xor(mx, off));
    }
    if (mx == -FLT_MAX) mx = mn - 1.0f;
    const float fill = mn - 1.0f;

    float sum = 0.f;
#pragma unroll
    for (int i = 0; i < 8; ++i) {
        f32x4 s = v[i];
        s.x = __expf(((msk >> (i * 4 + 0)) & 1u ? fill : s.x) - mx);
        s.y = __expf(((msk >> (i * 4 + 1)) & 1u ? fill : s.y) - mx);
        s.z = __expf(((msk >> (i * 4 + 2)) & 1u ? fill : s.z) - mx);
        s.w = __expf(((msk >> (i * 4 + 3)) & 1u ? fill : s.w) - mx);
        sum += s.x + s.y + s.z + s.w;
        v[i] = s;
    }
    for (int off = 32; off; off >>= 1) sum += __shfl_xor(sum, off);
    const float inv = 1.0f / sum;
    f32x4* po = (f32x4*)(S + (size_t)row * N_CLS);
#pragma unroll
    for (int i = 0; i < 8; ++i) {
        f32x4 s = v[i] * inv;
        __builtin_nontemporal_store(s, &po[i * 64 + lane]);
    }
}

__global__ __launch_bounds__(256) void softmax_kernel(float* __restrict__ S,
                                                      const float* __restrict__ cK) {
    const int w    = threadIdx.x >> 6;
    const int lane = threadIdx.x & 63;
    const float4* ck4 = (const float4*)cK;

    unsigned msk = 0;                         // row-invariant per-lane column mask
#pragma unroll
    for (int i = 0; i < 8; ++i) {
        float4 k = ck4[i * 64 + lane];
        if (k.x == 0.f) msk |= 1u << (i * 4 + 0);
        if (k.y == 0.f) msk |= 1u << (i * 4 + 1);
        if (k.z == 0.f) msk |= 1u << (i * 4 + 2);
        if (k.w == 0.f) msk |= 1u << (i * 4 + 3);
    }

    const int r0 = blockIdx.x * 16 + w * 4;   // 4 consecutive rows per wave
    f32x4 va[8], vb[8];

    sm_load_row(S, r0 + 0, lane, va);         // prologue
    sm_load_row(S, r0 + 1, lane, vb);         // row 1 in flight during row 0 compute
    sm_compute_store(S, r0 + 0, lane, msk, va);
    sm_load_row(S, r0 + 2, lane, va);
    sm_compute_store(S, r0 + 1, lane, msk, vb);
    sm_load_row(S, r0 + 3, lane, vb);
    sm_compute_store(S, r0 + 2, lane, msk, va);
    sm_compute_store(S, r0 + 3, lane, msk, vb);
}

extern "C" void kernel_launch(void* const* d_in, const int* in_sizes, int n_in,
                              void* d_out, int out_size, void* d_ws, size_t ws_size,
                              hipStream_t stream) {
    const float* X   = (const float*)d_in[0];   // (32768, 512)
    const float* muK = (const float*)d_in[1];   // (2048, 512)
    const float* cK  = (const float*)d_in[2];   // (2048,)
    float* out = (float*)d_out;                 // (32768, 2048)

    const size_t XN = (size_t)N_ROWS * DIM;     // 16.8M elems
    const size_t MN = (size_t)N_CLS * DIM;      // 1.05M elems
    const size_t need = (2 * XN + 2 * MN) * sizeof(short) + N_CLS * sizeof(float);

    dim3 grid(N_CLS / 128, N_ROWS / 128);

    if (ws_size >= need) {
        // ws layout: Xh 32MB | Xl 32MB | Mh 2MB | Ml 2MB | m2 8KB
        short* Xh = (short*)d_ws;
        short* Xl = Xh + XN;
        short* Mh = Xl + XN;
        short* Ml = Mh + MN;
        float* m2 = (float*)(Ml + MN);
        split_kernel<<<(int)(XN / 4 / 256), 256, 0, stream>>>(X, Xh, Xl);
        split_kernel<<<(int)(MN / 4 / 256), 256, 0, stream>>>(muK, Mh, Ml);
        m2_kernel<<<N_CLS, 256, 0, stream>>>(muK, m2);
        gemm_kernel<<<grid, 256, 0, stream>>>(Xh, Xl, Mh, Ml, m2, out);
    } else {
        float* m2f = (float*)d_ws;
        m2_kernel<<<N_CLS, 256, 0, stream>>>(muK, m2f);
        gemm_fallback<<<grid, 256, 0, stream>>>(X, muK, m2f, out);
    }
    softmax_kernel<<<N_ROWS / 16, 256, 0, stream>>>(out, cK);
}

// Round 9
// 586.672 us; speedup vs baseline: 1.0835x; 1.0835x over previous
//
#include <hip/hip_runtime.h>
#include <cfloat>

// Problem constants
#define N_ROWS 32768
#define N_CLS  2048
#define DIM    512

typedef __attribute__((ext_vector_type(8))) short short8;
typedef __attribute__((ext_vector_type(4))) short short4v;
typedef __attribute__((ext_vector_type(4))) float f32x4;

__device__ __forceinline__ unsigned f2bf_bits(float x) {
    union { float f; unsigned u; } a; a.f = x;
    return (a.u + 0x7fffu + ((a.u >> 16) & 1u)) >> 16;   // RNE
}
__device__ __forceinline__ float bf_to_f(unsigned bits) {
    union { unsigned u; float f; } a; a.u = bits << 16;
    return a.f;
}
__device__ __forceinline__ void split_bf(float x, short &h, short &l) {
    unsigned hb = f2bf_bits(x);
    h = (short)hb;
    float r = x - bf_to_f(hb);          // exact residual
    l = (short)f2bf_bits(r);
}

// ---------------- pre-split fp32 -> (hi, lo) bf16 arrays ----------------
__global__ __launch_bounds__(256) void split_kernel(const float* __restrict__ src,
                                                    short* __restrict__ hi,
                                                    short* __restrict__ lo) {
    int idx = blockIdx.x * 256 + threadIdx.x;     // one float4 per thread
    float4 v = ((const float4*)src)[idx];
    short h0, h1, h2, h3, l0, l1, l2, l3;
    split_bf(v.x, h0, l0); split_bf(v.y, h1, l1);
    split_bf(v.z, h2, l2); split_bf(v.w, h3, l3);
    ((short4v*)hi)[idx] = (short4v){h0, h1, h2, h3};
    ((short4v*)lo)[idx] = (short4v){l0, l1, l2, l3};
}

// ---------------- m2[j] = sum_d muK[j,d]^2 ----------------
__global__ __launch_bounds__(256) void m2_kernel(const float* __restrict__ muK,
                                                 float* __restrict__ m2) {
    const int j = blockIdx.x;
    const int t = threadIdx.x;
    const float* r = muK + (size_t)j * DIM;
    float a = r[t], b = r[t + 256];
    float s = a * a + b * b;
    for (int off = 32; off; off >>= 1) s += __shfl_xor(s, off);
    __shared__ float sw[4];
    if ((t & 63) == 0) sw[t >> 6] = s;
    __syncthreads();
    if (t == 0) m2[j] = sw[0] + sw[1] + sw[2] + sw[3];
}

#define GLDS16(g, l) __builtin_amdgcn_global_load_lds( \
    (const __attribute__((address_space(1))) unsigned int*)(g), \
    (__attribute__((address_space(3))) unsigned int*)(l), 16, 0, 0)

// ---------------- fused bf16x3 GEMM: one LDS residency, 3 MFMA streams ----------------
// S[i,j] = 2 * (Xh.Mh + Xh.Ml + Xl.Mh)[i,j] - m2[j]
// Per K-chunk (BK=32): stage Ash/Asl/Bsh/Bsl (4 x 8 KB), then 48 MFMAs.
// 16 rounds, 32 barriers total (vs 96 in concat-K) -> 3x MFMA per barrier drain.
// XOR bank swizzle (R7-verified, 0 conflicts): LDS slot (row,c) holds global
// 16B k-chunk (c ^ sigma(row)), sigma(row)=(row>>1)&3.
__global__ __launch_bounds__(256) void gemm_kernel(const short* __restrict__ Xh,
                                                   const short* __restrict__ Xl,
                                                   const short* __restrict__ Mh,
                                                   const short* __restrict__ Ml,
                                                   const float* __restrict__ m2,
                                                   float* __restrict__ S) {
    __shared__ __align__(16) short Ash[128 * 32];
    __shared__ __align__(16) short Asl[128 * 32];
    __shared__ __align__(16) short Bsh[128 * 32];
    __shared__ __align__(16) short Bsl[128 * 32];

    const int tid  = threadIdx.x;
    const int n0   = blockIdx.x * 128;   // class tile
    const int m0   = blockIdx.y * 128;   // row tile
    const int w    = tid >> 6;
    const int lane = tid & 63;
    const int wm   = (w >> 1) * 64;
    const int wn   = (w & 1) * 64;
    const int l16  = lane & 15;
    const int quad = lane >> 4;

    // staging chunk ids (16B chunks); LDS dest = uniform base + lane*16 (lane-linear).
    // Source k-chunk is XOR-swizzled by sigma(row) = (row>>1)&3 = (c>>3)&3.
    const int c0 = w * 128 + lane;
    const int c1 = c0 + 64;
    const size_t ga0 = (size_t)(m0 + (c0 >> 2)) * DIM + (size_t)(((c0 & 3) ^ ((c0 >> 3) & 3)) * 8);
    const size_t ga1 = (size_t)(m0 + (c1 >> 2)) * DIM + (size_t)(((c1 & 3) ^ ((c1 >> 3) & 3)) * 8);
    const size_t gb0 = (size_t)(n0 + (c0 >> 2)) * DIM + (size_t)(((c0 & 3) ^ ((c0 >> 3) & 3)) * 8);
    const size_t gb1 = (size_t)(n0 + (c1 >> 2)) * DIM + (size_t)(((c1 & 3) ^ ((c1 >> 3) & 3)) * 8);

    // reader swizzle: row bits [2:1] equal l16 bits [2:1] (wm, mt*16 are multiples of 16)
    const int sw = (quad ^ ((l16 >> 1) & 3)) * 8;

    f32x4 acc[4][4];
#pragma unroll
    for (int mt = 0; mt < 4; ++mt)
#pragma unroll
        for (int nt = 0; nt < 4; ++nt)
            acc[mt][nt] = (f32x4){0.f, 0.f, 0.f, 0.f};

#pragma unroll 1
    for (int kt2 = 0; kt2 < 16; ++kt2) {
        const int kk = kt2 * 32;
        __syncthreads();
        GLDS16(Xh + ga0 + kk, &Ash[c0 * 8]);
        GLDS16(Xh + ga1 + kk, &Ash[c1 * 8]);
        GLDS16(Xl + ga0 + kk, &Asl[c0 * 8]);
        GLDS16(Xl + ga1 + kk, &Asl[c1 * 8]);
        GLDS16(Mh + gb0 + kk, &Bsh[c0 * 8]);
        GLDS16(Mh + gb1 + kk, &Bsh[c1 * 8]);
        GLDS16(Ml + gb0 + kk, &Bsl[c0 * 8]);
        GLDS16(Ml + gb1 + kk, &Bsl[c1 * 8]);
        __syncthreads();

        short8 ah[4], al[4];
#pragma unroll
        for (int mt = 0; mt < 4; ++mt) {
            const int ro = (wm + mt * 16 + l16) * 32 + sw;
            ah[mt] = *(const short8*)&Ash[ro];
            al[mt] = *(const short8*)&Asl[ro];
        }
#pragma unroll
        for (int nt = 0; nt < 4; ++nt) {
            const int ro = (wn + nt * 16 + l16) * 32 + sw;
            short8 bh = *(const short8*)&Bsh[ro];
            short8 bl = *(const short8*)&Bsl[ro];
#pragma unroll
            for (int mt = 0; mt < 4; ++mt)
                acc[mt][nt] = __builtin_amdgcn_mfma_f32_16x16x32_bf16(ah[mt], bh, acc[mt][nt], 0, 0, 0);
#pragma unroll
            for (int mt = 0; mt < 4; ++mt)
                acc[mt][nt] = __builtin_amdgcn_mfma_f32_16x16x32_bf16(ah[mt], bl, acc[mt][nt], 0, 0, 0);
#pragma unroll
            for (int mt = 0; mt < 4; ++mt)
                acc[mt][nt] = __builtin_amdgcn_mfma_f32_16x16x32_bf16(al[mt], bh, acc[mt][nt], 0, 0, 0);
        }
    }

    // epilogue: C/D layout col=lane&15, row=quad*4+reg
#pragma unroll
    for (int nt = 0; nt < 4; ++nt) {
        int col = n0 + wn + nt * 16 + l16;
        float mm = m2[col];
#pragma unroll
        for (int mt = 0; mt < 4; ++mt) {
            int rbase = m0 + wm + mt * 16 + quad * 4;
#pragma unroll
            for (int r = 0; r < 4; ++r)
                S[(size_t)(rbase + r) * N_CLS + col] = 2.0f * acc[mt][nt][r] - mm;
        }
    }
}

// ---------------- round-1 fallback GEMM (in-kernel split; needs no big ws) ----------------
#define LDR 40
__global__ __launch_bounds__(256) void gemm_fallback(const float* __restrict__ X,
                                                     const float* __restrict__ muK,
                                                     const float* __restrict__ m2,
                                                     float* __restrict__ S) {
    __shared__ __align__(16) short Ah[128 * LDR];
    __shared__ __align__(16) short Al[128 * LDR];
    __shared__ __align__(16) short Bh[128 * LDR];
    __shared__ __align__(16) short Bl[128 * LDR];
    const int tid  = threadIdx.x;
    const int n0   = blockIdx.x * 128;
    const int m0   = blockIdx.y * 128;
    const int w    = tid >> 6;
    const int lane = tid & 63;
    const int wm   = (w >> 1) * 64;
    const int wn   = (w & 1) * 64;
    const int l16  = lane & 15;
    const int quad = lane >> 4;
    f32x4 acc[4][4];
#pragma unroll
    for (int mt = 0; mt < 4; ++mt)
#pragma unroll
        for (int nt = 0; nt < 4; ++nt)
            acc[mt][nt] = (f32x4){0.f, 0.f, 0.f, 0.f};
    for (int kt = 0; kt < DIM; kt += 32) {
        __syncthreads();
#pragma unroll
        for (int i = 0; i < 4; ++i) {
            int idx = tid + 256 * i;
            int row = idx >> 3;
            int c4  = (idx & 7) * 4;
            float4 fa = *(const float4*)(X + (size_t)(m0 + row) * DIM + kt + c4);
            float4 fb = *(const float4*)(muK + (size_t)(n0 + row) * DIM + kt + c4);
            short h0, h1, h2, h3, l0, l1, l2, l3;
            split_bf(fa.x, h0, l0); split_bf(fa.y, h1, l1);
            split_bf(fa.z, h2, l2); split_bf(fa.w, h3, l3);
            *(short4v*)&Ah[row * LDR + c4] = (short4v){h0, h1, h2, h3};
            *(short4v*)&Al[row * LDR + c4] = (short4v){l0, l1, l2, l3};
            split_bf(fb.x, h0, l0); split_bf(fb.y, h1, l1);
            split_bf(fb.z, h2, l2); split_bf(fb.w, h3, l3);
            *(short4v*)&Bh[row * LDR + c4] = (short4v){h0, h1, h2, h3};
            *(short4v*)&Bl[row * LDR + c4] = (short4v){l0, l1, l2, l3};
        }
        __syncthreads();
        short8 ah[4], al[4];
#pragma unroll
        for (int mt = 0; mt < 4; ++mt) {
            int r = wm + mt * 16 + l16;
            ah[mt] = *(const short8*)&Ah[r * LDR + quad * 8];
            al[mt] = *(const short8*)&Al[r * LDR + quad * 8];
        }
#pragma unroll
        for (int nt = 0; nt < 4; ++nt) {
            int r = wn + nt * 16 + l16;
            short8 bh = *(const short8*)&Bh[r * LDR + quad * 8];
            short8 bl = *(const short8*)&Bl[r * LDR + quad * 8];
#pragma unroll
            for (int mt = 0; mt < 4; ++mt)
                acc[mt][nt] = __builtin_amdgcn_mfma_f32_16x16x32_bf16(ah[mt], bh, acc[mt][nt], 0, 0, 0);
#pragma unroll
            for (int mt = 0; mt < 4; ++mt)
                acc[mt][nt] = __builtin_amdgcn_mfma_f32_16x16x32_bf16(ah[mt], bl, acc[mt][nt], 0, 0, 0);
#pragma unroll
            for (int mt = 0; mt < 4; ++mt)
                acc[mt][nt] = __builtin_amdgcn_mfma_f32_16x16x32_bf16(al[mt], bh, acc[mt][nt], 0, 0, 0);
        }
    }
#pragma unroll
    for (int nt = 0; nt < 4; ++nt) {
        int col = n0 + wn + nt * 16 + l16;
        float mm = m2[col];
#pragma unroll
        for (int mt = 0; mt < 4; ++mt) {
            int rbase = m0 + wm + mt * 16 + quad * 4;
#pragma unroll
            for (int r = 0; r < 4; ++r)
                S[(size_t)(rbase + r) * N_CLS + col] = 2.0f * acc[mt][nt][r] - mm;
        }
    }
}

// ---------------- masked row softmax: wave = 4 consecutive rows, 2-row pipeline ----------
// In-place. Cached loads, NT stores. Mask hoisted (row-invariant).
__device__ __forceinline__ void sm_load_row(float* S, int row, int lane, f32x4* v) {
    const f32x4* pi = (const f32x4*)(S + (size_t)row * N_CLS);
#pragma unroll
    for (int i = 0; i < 8; ++i) v[i] = pi[i * 64 + lane];
}

__device__ __forceinline__ void sm_compute_store(float* S, int row, int lane,
                                                 unsigned msk, f32x4* v) {
    float mn = FLT_MAX, mx = -FLT_MAX;
#pragma unroll
    for (int i = 0; i < 8; ++i) {
        f32x4 s = v[i];
        mn = fminf(mn, fminf(fminf(s.x, s.y), fminf(s.z, s.w)));
        if (!((msk >> (i * 4 + 0)) & 1u)) mx = fmaxf(mx, s.x);
        if (!((msk >> (i * 4 + 1)) & 1u)) mx = fmaxf(mx, s.y);
        if (!((msk >> (i * 4 + 2)) & 1u)) mx = fmaxf(mx, s.z);
        if (!((msk >> (i * 4 + 3)) & 1u)) mx = fmaxf(mx, s.w);
    }
    for (int off = 32; off; off >>= 1) {
        mn = fminf(mn, __shfl_xor(mn, off));
        mx = fmaxf(mx, __shfl_xor(mx, off));
    }
    if (mx == -FLT_MAX) mx = mn - 1.0f;
    const float fill = mn - 1.0f;

    float sum = 0.f;
#pragma unroll
    for (int i = 0; i < 8; ++i) {
        f32x4 s = v[i];
        s.x = __expf(((msk >> (i * 4 + 0)) & 1u ? fill : s.x) - mx);
        s.y = __expf(((msk >> (i * 4 + 1)) & 1u ? fill : s.y) - mx);
        s.z = __expf(((msk >> (i * 4 + 2)) & 1u ? fill : s.z) - mx);
        s.w = __expf(((msk >> (i * 4 + 3)) & 1u ? fill : s.w) - mx);
        sum += s.x + s.y + s.z + s.w;
        v[i] = s;
    }
    for (int off = 32; off; off >>= 1) sum += __shfl_xor(sum, off);
    const float inv = 1.0f / sum;
    f32x4* po = (f32x4*)(S + (size_t)row * N_CLS);
#pragma unroll
    for (int i = 0; i < 8; ++i) {
        f32x4 s = v[i] * inv;
        __builtin_nontemporal_store(s, &po[i * 64 + lane]);
    }
}

__global__ __launch_bounds__(256) void softmax_kernel(float* __restrict__ S,
                                                      const float* __restrict__ cK) {
    const int w    = threadIdx.x >> 6;
    const int lane = threadIdx.x & 63;
    const float4* ck4 = (const float4*)cK;

    unsigned msk = 0;                         // row-invariant per-lane column mask
#pragma unroll
    for (int i = 0; i < 8; ++i) {
        float4 k = ck4[i * 64 + lane];
        if (k.x == 0.f) msk |= 1u << (i * 4 + 0);
        if (k.y == 0.f) msk |= 1u << (i * 4 + 1);
        if (k.z == 0.f) msk |= 1u << (i * 4 + 2);
        if (k.w == 0.f) msk |= 1u << (i * 4 + 3);
    }

    const int r0 = blockIdx.x * 16 + w * 4;   // 4 consecutive rows per wave
    f32x4 va[8], vb[8];

    sm_load_row(S, r0 + 0, lane, va);         // prologue
    sm_load_row(S, r0 + 1, lane, vb);         // row 1 in flight during row 0 compute
    sm_compute_store(S, r0 + 0, lane, msk, va);
    sm_load_row(S, r0 + 2, lane, va);
    sm_compute_store(S, r0 + 1, lane, msk, vb);
    sm_load_row(S, r0 + 3, lane, vb);
    sm_compute_store(S, r0 + 2, lane, msk, va);
    sm_compute_store(S, r0 + 3, lane, msk, vb);
}

extern "C" void kernel_launch(void* const* d_in, const int* in_sizes, int n_in,
                              void* d_out, int out_size, void* d_ws, size_t ws_size,
                              hipStream_t stream) {
    const float* X   = (const float*)d_in[0];   // (32768, 512)
    const float* muK = (const float*)d_in[1];   // (2048, 512)
    const float* cK  = (const float*)d_in[2];   // (2048,)
    float* out = (float*)d_out;                 // (32768, 2048)

    const size_t XN = (size_t)N_ROWS * DIM;     // 16.8M elems
    const size_t MN = (size_t)N_CLS * DIM;      // 1.05M elems
    const size_t need = (2 * XN + 2 * MN) * sizeof(short) + N_CLS * sizeof(float);

    dim3 grid(N_CLS / 128, N_ROWS / 128);

    if (ws_size >= need) {
        // ws layout: Xh 32MB | Xl 32MB | Mh 2MB | Ml 2MB | m2 8KB
        short* Xh = (short*)d_ws;
        short* Xl = Xh + XN;
        short* Mh = Xl + XN;
        short* Ml = Mh + MN;
        float* m2 = (float*)(Ml + MN);
        split_kernel<<<(int)(XN / 4 / 256), 256, 0, stream>>>(X, Xh, Xl);
        split_kernel<<<(int)(MN / 4 / 256), 256, 0, stream>>>(muK, Mh, Ml);
        m2_kernel<<<N_CLS, 256, 0, stream>>>(muK, m2);
        gemm_kernel<<<grid, 256, 0, stream>>>(Xh, Xl, Mh, Ml, m2, out);
    } else {
        float* m2f = (float*)d_ws;
        m2_kernel<<<N_CLS, 256, 0, stream>>>(muK, m2f);
        gemm_fallback<<<grid, 256, 0, stream>>>(X, muK, m2f, out);
    }
    softmax_kernel<<<N_ROWS / 16, 256, 0, stream>>>(out, cK);
}